// Round 8
// baseline (481.393 us; speedup 1.0000x reference)
//
#include <hip/hip_runtime.h>

// LinearAttention: b=16, n=4096, dim=512, H=8, D=64, inner=512. T=65536 tokens.
// I/O dtype: fp32 (per reference). Compute: bf16 MFMA, fp32 accumulate.
//
// Algebraic form: out[t] = sum_h z_h(t) * (q'_h[t] @ kv_h) @ Wout_h
//                        = (z .* q') @ Pcat,  Pcat_b[c][h*64+d] = sum_e kv_h[d][e] Wout[c][h*64+e]
//
// ws layout (~139 MiB):
//   wq_bf  [1536x512 bf16]  W_qkv converted + ROW-PERMUTED (q | per-head k|v)
//   wo_bf  [ 512x512 bf16]  converted W_out
//   wsq    [65536x512 bf16] q' = act(x@Wq^T); scaled in place by apply_z
//   xb     [65536x512 bf16] x converted once; REUSED as P after gemm_qkv
//   kvglob [128 x 64x80 f32] kv accumulator (atomicAdd), col e=64 = ksum
//   ksum_bf[128 x 64 bf16]  per-(b,h) k-sum vector
//
// R7->R8: GEMMs moved 256->512 threads (8 waves, wave owns 32x64: acc 32 AGPR
// vs 64) to lift the VGPR+AGPR occupancy cap (was ~2 blocks/CU). Same proven
// 2-phase __syncthreads double-buffer; sync structure UNCHANGED (R6 lesson).

typedef unsigned short u16;
typedef u16 u16x4 __attribute__((ext_vector_type(4)));
typedef u16 u16x8 __attribute__((ext_vector_type(8)));
typedef __bf16 bf16x8 __attribute__((ext_vector_type(8)));
typedef float f32x4 __attribute__((ext_vector_type(4)));

__device__ __forceinline__ float bf2f(u16 x) {
    union { unsigned u; float f; } t; t.u = ((unsigned)x) << 16; return t.f;
}
__device__ __forceinline__ u16 f2bf(float f) {
    union { float f; unsigned u; } t; t.f = f;
    unsigned r = t.u + 0x7fffu + ((t.u >> 16) & 1u);   // RNE
    return (u16)(r >> 16);
}
__device__ __forceinline__ float act_fn(float v) {     // 1 + elu
    return v > 0.0f ? v + 1.0f : __expf(v);
}
__device__ __forceinline__ void cvt8(const float* __restrict__ s, u16* __restrict__ d) {
    f32x4 lo = *(const f32x4*)s;
    f32x4 hi = *(const f32x4*)(s + 4);
    u16x8 o = { f2bf(lo[0]), f2bf(lo[1]), f2bf(lo[2]), f2bf(lo[3]),
                f2bf(hi[0]), f2bf(hi[1]), f2bf(hi[2]), f2bf(hi[3]) };
    *(u16x8*)d = o;
}
// async global->LDS, 16B per lane. LDS dest = wave-uniform base + lane*16.
__device__ __forceinline__ void gld16(const u16* g, u16* l) {
    __builtin_amdgcn_global_load_lds(
        (__attribute__((address_space(1))) const void*)g,
        (__attribute__((address_space(3))) void*)l, 16, 0, 0);
}

// ---------------------------------------------------------------------------
// convert_all: x (4,194,304 x8 units) -> xb ; W_qkv (98,304 units) -> wq_bf
// with the head-interleaved row permutation ; W_out (32,768) -> wo_bf ;
// zero kvglob (81,920 f32 = 10,240 x8 units). 17,216 x 256 exact.
// ---------------------------------------------------------------------------
__global__ __launch_bounds__(256) void convert_all(const float* __restrict__ x,
                                                   const float* __restrict__ Wqkv,
                                                   const float* __restrict__ Wout,
                                                   u16* __restrict__ xb,
                                                   u16* __restrict__ wq,
                                                   u16* __restrict__ wo,
                                                   float* __restrict__ kvg)
{
    size_t u = (size_t)blockIdx.x * 256 + threadIdx.x;
    if (u < 4194304ull) {
        cvt8(x + u * 8, xb + u * 8);
    } else if (u < 4292608ull) {
        u -= 4194304ull;                       // dest unit within wq_bf
        const int drow = (int)(u >> 6);
        int srow;
        if (drow < 512) srow = drow;
        else {
            const int t = drow - 512, h = t >> 7, j = t & 127;
            srow = (j < 64) ? (512 + h * 64 + j) : (1024 + h * 64 + (j - 64));
        }
        cvt8(Wqkv + (size_t)srow * 512 + (u & 63) * 8, wq + u * 8);
    } else if (u < 4325376ull) {
        u -= 4292608ull; cvt8(Wout + u * 8, wo + u * 8);
    } else {
        u -= 4325376ull;
        f32x4 z = { 0.f, 0.f, 0.f, 0.f };
        *(f32x4*)&kvg[u * 8] = z;
        *(f32x4*)&kvg[u * 8 + 4] = z;
    }
}

// ---------------------------------------------------------------------------
// gemm_qkv: C128x128 tile of x @ Wqkv_perm^T, K=512, 2-phase double-buffered
// global_load_lds staging (PROVEN sync structure). 512 thr / 8 waves; wave w
// owns rows wr=(w>>1)*32 (+0/+16), cols wc=(w&1)*64 (+0..3*16): acc 2x4.
// Staging: 512 lanes x 16B = one 8KB half-tile per gld16 issue (1 A + 1 B
// per wave per K-step).
// Col-tiles 0..3 -> q: act + store to wsq.  Col-tiles 4..11 -> head h=nt-4:
// cols 0..63 = k, 64..127 = v; transpose to KT/VT (overlaying the dead LDS
// double buffer), kv[d][e] += KT@VT^T (VT row 64 = ones -> e=64 = ksum),
// atomicAdd into kvglob[b*8+h].
// ---------------------------------------------------------------------------
__global__ __launch_bounds__(512, 4) void gemm_qkv(const u16* __restrict__ A,
                                                   const u16* __restrict__ Bw,
                                                   u16* __restrict__ Cq,
                                                   float* __restrict__ kvglob)
{
    __shared__ u16 SMF[16384];     // 32 KB: buf b at b*8192 (As 4096 | Bs 4096)
    const int nt = blockIdx.x;     // 0..11 col-tile
    const int mt = blockIdx.y;     // 0..511 M-tile
    const size_t row0 = (size_t)mt * 128;
    const int col0 = nt * 128;
    const int tid = threadIdx.x, wave = tid >> 6, lane = tid & 63;
    const int frow = lane & 15, quad = lane >> 4;
    const int wr = (wave >> 1) * 32, wc = (wave & 1) * 64;

    f32x4 acc[2][4] = {};

    // staging: ch = tid; row = ch>>2 (0..127), col = (ch&3)*8; one issue each
    const int r0 = tid >> 2, c0 = (tid & 3) * 8;
    const u16* gA0 = A + (row0 + r0) * 512 + c0;
    const u16* gB0 = Bw + (size_t)(col0 + r0) * 512 + c0;

#define QKV_STAGE(buf, k0) do {                                   \
        u16* As_ = SMF + (buf) * 8192;                            \
        u16* Bs_ = As_ + 4096;                                    \
        gld16(gA0 + (k0), As_ + wave * 512);                      \
        gld16(gB0 + (k0), Bs_ + wave * 512);                      \
    } while (0)

    QKV_STAGE(0, 0);
    __syncthreads();               // implicit vmcnt(0): buf0 ready
    int cur = 0;
    for (int t = 0; t < 16; ++t) {
        if (t < 15) QKV_STAGE(cur ^ 1, (t + 1) * 32);   // prefetch next tile
        const u16* As_ = SMF + cur * 8192;
        const u16* Bs_ = As_ + 4096;
        bf16x8 af[2], bfr[4];
#pragma unroll
        for (int mi = 0; mi < 2; ++mi)
            af[mi] = *(const bf16x8*)&As_[(wr + mi * 16 + frow) * 32 + quad * 8];
#pragma unroll
        for (int ni = 0; ni < 4; ++ni)
            bfr[ni] = *(const bf16x8*)&Bs_[(wc + ni * 16 + frow) * 32 + quad * 8];
#pragma unroll
        for (int mi = 0; mi < 2; ++mi)
#pragma unroll
            for (int ni = 0; ni < 4; ++ni)
                acc[mi][ni] = __builtin_amdgcn_mfma_f32_16x16x32_bf16(af[mi], bfr[ni], acc[mi][ni], 0, 0, 0);
        __syncthreads();           // drains vmcnt(0): prefetched buf ready
        cur ^= 1;
    }
#undef QKV_STAGE

    if (col0 < 512) {
        // q epilogue: C/D layout col = lane&15, row = quad*4 + reg [m89/m91]
#pragma unroll
        for (int mi = 0; mi < 2; ++mi) {
#pragma unroll
            for (int ni = 0; ni < 4; ++ni) {
                const int c = col0 + wc + ni * 16 + frow;
                const size_t rbase = row0 + wr + mi * 16 + quad * 4;
#pragma unroll
                for (int reg = 0; reg < 4; ++reg)
                    Cq[(rbase + reg) * 512 + c] = f2bf(act_fn(acc[mi][ni][reg]));
            }
        }
        return;
    }

    // ---- kv epilogue (head h = nt-4), KT/VT overlay the dead double buffer.
    // Safe: main loop ends with __syncthreads(); ones region (u16 9216..10367)
    // is disjoint from KT (0..4607) and VT rows 0..63 (4608..9215), and is
    // only read after the half-loop barriers.
    u16* KT = SMF;                 // [64][72] k^T
    u16* VT = SMF + 4608;          // [80][72] v^T; row 64 = ones
    for (int i = tid; i < 16 * 72; i += 512)
        VT[64 * 72 + i] = (i < 64) ? (u16)0x3F80 : (u16)0;

    const bool is_k = (wc == 0);   // even waves hold k cols, odd hold v cols
    f32x4 kvacc[5] = {};           // e-tiles; meaningful on waves 0..3

#pragma unroll
    for (int half = 0; half < 2; ++half) {
        __syncthreads();           // prior KT/VT readers (and ones writes) done
        if ((wave >> 2) == half) { // waves 0-3: token rows 0..63; 4-7: 64..127
#pragma unroll
            for (int mi = 0; mi < 2; ++mi) {
                const int n0 = wr + mi * 16 + quad * 4 - half * 64;   // 0..60
#pragma unroll
                for (int ni = 0; ni < 4; ++ni) {
                    const int cl = wc + ni * 16 + frow;               // 0..127
                    u16x4 o2;
#pragma unroll
                    for (int reg = 0; reg < 4; ++reg) {
                        float v = acc[mi][ni][reg];
                        if (is_k) v = act_fn(v);
                        o2[reg] = f2bf(v);
                    }
                    if (is_k) *(u16x4*)&KT[cl * 72 + n0] = o2;
                    else      *(u16x4*)&VT[(cl - 64) * 72 + n0] = o2;
                }
            }
        }
        __syncthreads();
        // kv[d][e] += KT@VT^T over this half's 64 tokens (waves 0-3 only)
        if (wave < 4) {
#pragma unroll
            for (int c = 0; c < 2; ++c) {
                bf16x8 af2 = *(const bf16x8*)&KT[(wave * 16 + frow) * 72 + c * 32 + quad * 8];
#pragma unroll
                for (int et = 0; et < 5; ++et) {
                    bf16x8 bf2 = *(const bf16x8*)&VT[(et * 16 + frow) * 72 + c * 32 + quad * 8];
                    kvacc[et] = __builtin_amdgcn_mfma_f32_16x16x32_bf16(af2, bf2, kvacc[et], 0, 0, 0);
                }
            }
        }
    }

    if (wave < 4) {
        const int b = mt >> 5, h = nt - 4;
        float* dst = kvglob + (size_t)(b * 8 + h) * 5120;
#pragma unroll
        for (int et = 0; et < 5; ++et) {
            const int e = et * 16 + frow;
            if (e <= 64) {
#pragma unroll
                for (int reg = 0; reg < 4; ++reg) {
                    const int d = wave * 16 + quad * 4 + reg;
                    atomicAdd(&dst[d * 80 + e], kvacc[et][reg]);
                }
            }
        }
    }
}

// ---------------------------------------------------------------------------
// make_P: one block per (b,h). P_b[c][h*64+d] = sum_e Wout[c][h*64+e]*kv[d][e]
// via MFMA (A = Wout rows from global, L2-resident; B = kv rows from LDS).
// Also extracts ksum_bf[bh][d] = kvglob col e=64. 512x64x64 GEMM per block.
// ---------------------------------------------------------------------------
__global__ __launch_bounds__(256) void make_P(const float* __restrict__ kvglob,
                                              const u16* __restrict__ wo,
                                              u16* __restrict__ P,
                                              u16* __restrict__ ksum)
{
    __shared__ u16 kvb[64 * 72];   // kv[d][e] bf16, pad 72
    const int bh = blockIdx.x, b = bh >> 3, h = bh & 7;
    const int tid = threadIdx.x, wave = tid >> 6, lane = tid & 63;
    const int frow = lane & 15, quad = lane >> 4;
    const float* src = kvglob + (size_t)bh * 5120;

    for (int i = tid; i < 4096; i += 256)
        kvb[(i >> 6) * 72 + (i & 63)] = f2bf(src[(i >> 6) * 80 + (i & 63)]);
    if (tid < 64) ksum[bh * 64 + tid] = f2bf(src[tid * 80 + 64]);
    __syncthreads();

    f32x4 acc[8][4] = {};          // m = Wout-row tile (wave*128..+128), n = d
    const int m0 = wave * 128;
#pragma unroll
    for (int k2 = 0; k2 < 2; ++k2) {           // e-chunk of 32
        bf16x8 bfr[4];
#pragma unroll
        for (int ni = 0; ni < 4; ++ni)
            bfr[ni] = *(const bf16x8*)&kvb[(ni * 16 + frow) * 72 + k2 * 32 + quad * 8];
#pragma unroll
        for (int mi = 0; mi < 8; ++mi) {
            bf16x8 af = *(const bf16x8*)&wo[(size_t)(m0 + mi * 16 + frow) * 512 + h * 64 + k2 * 32 + quad * 8];
#pragma unroll
            for (int ni = 0; ni < 4; ++ni)
                acc[mi][ni] = __builtin_amdgcn_mfma_f32_16x16x32_bf16(af, bfr[ni], acc[mi][ni], 0, 0, 0);
        }
    }

    u16* Pb = P + (size_t)b * 262144;
#pragma unroll
    for (int mi = 0; mi < 8; ++mi) {
#pragma unroll
        for (int ni = 0; ni < 4; ++ni) {
            const int d = ni * 16 + frow;      // C/D: col = lane&15
#pragma unroll
            for (int reg = 0; reg < 4; ++reg) {
                const int c = m0 + mi * 16 + quad * 4 + reg;
                Pb[(size_t)c * 512 + h * 64 + d] = f2bf(acc[mi][ni][reg]);
            }
        }
    }
}

// ---------------------------------------------------------------------------
// apply_z: q''[t][i] = q'[t][i] / max(q'_h(t)·ksum_h, eps), h = i/64.
// COALESCED: one wave per token row — 64 lanes x 16B = the whole 1KB row;
// per-head denominator via 3-step shfl_xor within 8-lane groups; lane's
// ksum slice (8 cols) held in regs for the whole block. 1024 blocks x 256,
// 64 tokens/block (batch-aligned), 16 tokens/wave.
// ---------------------------------------------------------------------------
__global__ __launch_bounds__(256) void apply_z(u16* __restrict__ qio,
                                               const u16* __restrict__ ksum)
{
    const int tid = threadIdx.x, wave = tid >> 6, lane = tid & 63;
    const int t0 = blockIdx.x * 64 + wave * 16;
    const int b = blockIdx.x >> 6;             // 64 blocks per batch

    u16x8 k8 = *(const u16x8*)&ksum[b * 512 + lane * 8];
    float kf[8];
#pragma unroll
    for (int e = 0; e < 8; ++e) kf[e] = bf2f(k8[e]);

    for (int it = 0; it < 16; ++it) {
        u16* row = qio + (size_t)(t0 + it) * 512 + lane * 8;
        u16x8 q8 = *(const u16x8*)row;
        float den = 0.f;
#pragma unroll
        for (int e = 0; e < 8; ++e) den += bf2f(q8[e]) * kf[e];
        den += __shfl_xor(den, 1);
        den += __shfl_xor(den, 2);
        den += __shfl_xor(den, 4);             // all 8 lanes of head group
        const float z = 1.0f / fmaxf(den, 1e-4f);
        u16x8 o;
#pragma unroll
        for (int e = 0; e < 8; ++e) o[e] = f2bf(bf2f(q8[e]) * z);
        *(u16x8*)row = o;
    }
}

// ---------------------------------------------------------------------------
// gemm_final: out[t][c] (fp32) = sum_i q''[t][i] * P_b[c][i] + bias[c].
// B matrix is per-batch (b = mt>>5), 512 KB, L2-resident. PROVEN 2-phase
// dbuf global_load_lds staging; 512 thr / 8 waves (acc 2x4, 32 AGPR).
// ---------------------------------------------------------------------------
__global__ __launch_bounds__(512, 4) void gemm_final(const u16* __restrict__ A,
                                                     const u16* __restrict__ P,
                                                     float* __restrict__ C,
                                                     const float* __restrict__ bias)
{
    __shared__ u16 SMF[16384];
    const int nt = blockIdx.x;     // 0..3 col-tile
    const int mt = blockIdx.y;     // 0..511 M-tile
    const size_t row0 = (size_t)mt * 128;
    const int col0 = nt * 128;
    const u16* Bw = P + (size_t)(mt >> 5) * 262144;
    const int tid  = threadIdx.x;
    const int wave = tid >> 6, lane = tid & 63;
    const int wr = (wave >> 1) * 32, wc = (wave & 1) * 64;
    const int frow = lane & 15, quad = lane >> 4;

    f32x4 acc[2][4] = {};

    const int r0 = tid >> 2, c0 = (tid & 3) * 8;
    const u16* gA0 = A + (row0 + r0) * 512 + c0;
    const u16* gB0 = Bw + (size_t)(col0 + r0) * 512 + c0;

#define OUT_STAGE(buf, k0) do {                                   \
        u16* As_ = SMF + (buf) * 8192;                            \
        u16* Bs_ = As_ + 4096;                                    \
        gld16(gA0 + (k0), As_ + wave * 512);                      \
        gld16(gB0 + (k0), Bs_ + wave * 512);                      \
    } while (0)

    OUT_STAGE(0, 0);
    __syncthreads();
    int cur = 0;
    for (int t = 0; t < 16; ++t) {
        if (t < 15) OUT_STAGE(cur ^ 1, (t + 1) * 32);
        const u16* As_ = SMF + cur * 8192;
        const u16* Bs_ = As_ + 4096;
        bf16x8 af[2], bfr[4];
#pragma unroll
        for (int mi = 0; mi < 2; ++mi)
            af[mi] = *(const bf16x8*)&As_[(wr + mi * 16 + frow) * 32 + quad * 8];
#pragma unroll
        for (int ni = 0; ni < 4; ++ni)
            bfr[ni] = *(const bf16x8*)&Bs_[(wc + ni * 16 + frow) * 32 + quad * 8];
#pragma unroll
        for (int mi = 0; mi < 2; ++mi)
#pragma unroll
            for (int ni = 0; ni < 4; ++ni)
                acc[mi][ni] = __builtin_amdgcn_mfma_f32_16x16x32_bf16(af[mi], bfr[ni], acc[mi][ni], 0, 0, 0);
        __syncthreads();
        cur ^= 1;
    }
#undef OUT_STAGE

#pragma unroll
    for (int mi = 0; mi < 2; ++mi) {
#pragma unroll
        for (int ni = 0; ni < 4; ++ni) {
            const int c = col0 + wc + ni * 16 + frow;
            const float bv = bias[c];
            const size_t rbase = row0 + wr + mi * 16 + quad * 4;
#pragma unroll
            for (int reg = 0; reg < 4; ++reg)
                C[(rbase + reg) * 512 + c] = acc[mi][ni][reg] + bv;
        }
    }
}

extern "C" void kernel_launch(void* const* d_in, const int* in_sizes, int n_in,
                              void* d_out, int out_size, void* d_ws, size_t ws_size,
                              hipStream_t stream)
{
    const float* x    = (const float*)d_in[0];   // [65536, 512] fp32
    const float* Wqkv = (const float*)d_in[1];   // [1536, 512]  fp32
    const float* Wout = (const float*)d_in[2];   // [512, 512]   fp32
    const float* bout = (const float*)d_in[3];   // [512]        fp32
    float* out = (float*)d_out;                  // [65536, 512] fp32
    char* ws = (char*)d_ws;

    u16*   wq_bf  = (u16*)ws;                      //   1,572,864 B
    u16*   wo_bf  = (u16*)(ws + 1572864ull);       //     524,288 B
    u16*   wsq    = (u16*)(ws + 2097152ull);       //  67,108,864 B
    u16*   xb     = (u16*)(ws + 69206016ull);      //  67,108,864 B (P reuses this)
    u16*   P      = xb;                            //   8,388,608 B (after gemm_qkv)
    float* kvglob = (float*)(ws + 136314880ull);   //   2,621,440 B
    u16*   ksum   = (u16*)(ws + 138936320ull);     //      65,536 B -> 139,001,856

    // 0) x -> bf16, weights -> bf16 (W_qkv row-permuted), zero kv accumulator
    convert_all<<<17216, 256, 0, stream>>>(x, Wqkv, Wout, xb, wq_bf, wo_bf, kvglob);
    // 1) fused qkv GEMM: q' -> wsq ; per-head kv outer-product -> kvglob
    gemm_qkv<<<dim3(12, 512), 512, 0, stream>>>(xb, wq_bf, wsq, kvglob);
    // 2) P_b = kv_h @ Wout_h (per bh) ; extract ksum  (xb dead -> P reuses it)
    make_P<<<128, 256, 0, stream>>>(kvglob, wo_bf, P, ksum);
    // 3) q' *= z (per token/head scalar), in place — coalesced wave-per-token
    apply_z<<<1024, 256, 0, stream>>>(wsq, ksum);
    // 4) out = q'' @ P_b^T + b_out -> d_out (fp32)
    gemm_final<<<dim3(4, 512), 512, 0, stream>>>(wsq, P, out, bout);
}

// Round 9
// 448.749 us; speedup vs baseline: 1.0727x; 1.0727x over previous
//
#include <hip/hip_runtime.h>

// LinearAttention: b=16, n=4096, dim=512, H=8, D=64, inner=512. T=65536 tokens.
// I/O dtype: fp32 (per reference). Compute: bf16 MFMA, fp32 accumulate.
//
// Algebraic form: out[t] = sum_h z_h(t) * (q'_h[t] @ kv_h) @ Wout_h
//                        = (z .* q') @ Pcat,  Pcat_b[c][h*64+d] = sum_e kv_h[d][e] Wout[c][h*64+e]
// z is a per-(token,head) scalar and the out-GEMM is linear in the q' row, so
// z is applied to the fp32 ACCUMULATOR of gemm_final (denominator computed
// in-GEMM via a broadcast-B MFMA against ksum) — no apply_z pass at all.
//
// ws layout (~139 MiB):
//   wq_bf  [1536x512 bf16]  W_qkv converted + ROW-PERMUTED (q | per-head k|v)
//   wo_bf  [ 512x512 bf16]  converted W_out
//   wsq    [65536x512 bf16] q' = act(x@Wq^T)  (UNscaled; z applied in gemm_final)
//   xb     [65536x512 bf16] x converted once; REUSED as P after gemm_qkv
//   kvglob [128 x 64x80 f32] kv accumulator (atomicAdd), col e=64 = ksum
//   ksum_bf[16 x 512 bf16]  per-batch concatenated k-sum (h*64+d)
//
// R8->R9: BK 32->64 in both GEMMs (halves barrier-drain count; compute/step
// doubles to cover load latency) + T2 XOR-swizzle applied BOTH-sides (rule
// #21: pre-swizzled global source + swizzled ds_read, LDS linear) to kill the
// 16-way [row][128B] conflict. Sync skeleton = proven 2-phase __syncthreads
// double-buffer, UNCHANGED (R6 lesson).

typedef unsigned short u16;
typedef u16 u16x4 __attribute__((ext_vector_type(4)));
typedef u16 u16x8 __attribute__((ext_vector_type(8)));
typedef __bf16 bf16x8 __attribute__((ext_vector_type(8)));
typedef float f32x4 __attribute__((ext_vector_type(4)));

__device__ __forceinline__ float bf2f(u16 x) {
    union { unsigned u; float f; } t; t.u = ((unsigned)x) << 16; return t.f;
}
__device__ __forceinline__ u16 f2bf(float f) {
    union { float f; unsigned u; } t; t.f = f;
    unsigned r = t.u + 0x7fffu + ((t.u >> 16) & 1u);   // RNE
    return (u16)(r >> 16);
}
__device__ __forceinline__ float act_fn(float v) {     // 1 + elu
    return v > 0.0f ? v + 1.0f : __expf(v);
}
__device__ __forceinline__ void cvt8(const float* __restrict__ s, u16* __restrict__ d) {
    f32x4 lo = *(const f32x4*)s;
    f32x4 hi = *(const f32x4*)(s + 4);
    u16x8 o = { f2bf(lo[0]), f2bf(lo[1]), f2bf(lo[2]), f2bf(lo[3]),
                f2bf(hi[0]), f2bf(hi[1]), f2bf(hi[2]), f2bf(hi[3]) };
    *(u16x8*)d = o;
}
// async global->LDS, 16B per lane. LDS dest = wave-uniform base + lane*16.
__device__ __forceinline__ void gld16(const u16* g, u16* l) {
    __builtin_amdgcn_global_load_lds(
        (__attribute__((address_space(1))) const void*)g,
        (__attribute__((address_space(3))) void*)l, 16, 0, 0);
}

// ---------------------------------------------------------------------------
// convert_all: x (4,194,304 x8 units) -> xb ; W_qkv (98,304 units) -> wq_bf
// with the head-interleaved row permutation ; W_out (32,768) -> wo_bf ;
// zero kvglob (81,920 f32 = 10,240 x8 units). 17,216 x 256 exact.
// ---------------------------------------------------------------------------
__global__ __launch_bounds__(256) void convert_all(const float* __restrict__ x,
                                                   const float* __restrict__ Wqkv,
                                                   const float* __restrict__ Wout,
                                                   u16* __restrict__ xb,
                                                   u16* __restrict__ wq,
                                                   u16* __restrict__ wo,
                                                   float* __restrict__ kvg)
{
    size_t u = (size_t)blockIdx.x * 256 + threadIdx.x;
    if (u < 4194304ull) {
        cvt8(x + u * 8, xb + u * 8);
    } else if (u < 4292608ull) {
        u -= 4194304ull;                       // dest unit within wq_bf
        const int drow = (int)(u >> 6);
        int srow;
        if (drow < 512) srow = drow;
        else {
            const int t = drow - 512, h = t >> 7, j = t & 127;
            srow = (j < 64) ? (512 + h * 64 + j) : (1024 + h * 64 + (j - 64));
        }
        cvt8(Wqkv + (size_t)srow * 512 + (u & 63) * 8, wq + u * 8);
    } else if (u < 4325376ull) {
        u -= 4292608ull; cvt8(Wout + u * 8, wo + u * 8);
    } else {
        u -= 4325376ull;
        f32x4 z = { 0.f, 0.f, 0.f, 0.f };
        *(f32x4*)&kvg[u * 8] = z;
        *(f32x4*)&kvg[u * 8 + 4] = z;
    }
}

// ---------------------------------------------------------------------------
// gemm_qkv: C128x128 tile of x @ Wqkv_perm^T, K=512, 8 K-steps of BK=64.
// 2-phase __syncthreads double-buffer (proven), 512 thr / 8 waves; wave owns
// 32x64 (acc 2x4). T2 swizzle: LDS [128][64] u16 stays LINEAR; global source
// per-chunk col16 = (ch&7)^(row&7); ds_read applies slot^(row&7). 64 lanes of
// a wave land 2/bank (free) instead of 16-way.
// Col-tiles 0..3 -> q: act + store to wsq.  Col-tiles 4..11 -> head h=nt-4:
// kv epilogue (KT/VT overlay buf0; last compute reads buf1 -> disjoint).
// ---------------------------------------------------------------------------
__global__ __launch_bounds__(512, 4) void gemm_qkv(const u16* __restrict__ A,
                                                   const u16* __restrict__ Bw,
                                                   u16* __restrict__ Cq,
                                                   float* __restrict__ kvglob)
{
    __shared__ u16 SMF[32768];     // 64 KB: buf b at b*16384 (As 8192 | Bs 8192)
    const int nt = blockIdx.x;     // 0..11 col-tile
    const int mt = blockIdx.y;     // 0..511 M-tile
    const size_t row0 = (size_t)mt * 128;
    const int col0 = nt * 128;
    const int tid = threadIdx.x, wave = tid >> 6, lane = tid & 63;
    const int frow = lane & 15, quad = lane >> 4;
    const int wr = (wave >> 1) * 32, wc = (wave & 1) * 64;

    f32x4 acc[2][4] = {};

    // staging chunks (16B each): ch in [0,1024) covers 128x64; row = ch>>3;
    // LDS linear at u16 ch*8; SOURCE col16 = (ch&7)^(row&7)  [T2 involution]
    const int ch0 = wave * 64 + lane, ch1 = 512 + ch0;
    const int ar0 = ch0 >> 3, ac0 = ((ch0 & 7) ^ (ar0 & 7)) * 8;
    const int ar1 = ch1 >> 3, ac1 = ((ch1 & 7) ^ (ar1 & 7)) * 8;
    const u16* gA0 = A + (row0 + ar0) * 512 + ac0;
    const u16* gA1 = A + (row0 + ar1) * 512 + ac1;
    const u16* gB0 = Bw + (size_t)(col0 + ar0) * 512 + ac0;
    const u16* gB1 = Bw + (size_t)(col0 + ar1) * 512 + ac1;

#define QKV_STAGE(buf, k0) do {                                   \
        u16* As_ = SMF + (buf) * 16384;                           \
        u16* Bs_ = As_ + 8192;                                    \
        gld16(gA0 + (k0), As_ + wave * 512);                      \
        gld16(gA1 + (k0), As_ + 4096 + wave * 512);               \
        gld16(gB0 + (k0), Bs_ + wave * 512);                      \
        gld16(gB1 + (k0), Bs_ + 4096 + wave * 512);               \
    } while (0)

    QKV_STAGE(0, 0);
    __syncthreads();               // implicit vmcnt(0): buf0 ready
    int cur = 0;
    for (int t = 0; t < 8; ++t) {
        if (t < 7) QKV_STAGE(cur ^ 1, (t + 1) * 64);    // prefetch next tile
        const u16* As_ = SMF + cur * 16384;
        const u16* Bs_ = As_ + 8192;
#pragma unroll
        for (int kk = 0; kk < 2; ++kk) {
            const int cbase = kk * 32 + quad * 8;
            bf16x8 af[2], bfr[4];
#pragma unroll
            for (int mi = 0; mi < 2; ++mi) {
                const int r = wr + mi * 16 + frow;
                af[mi] = *(const bf16x8*)&As_[r * 64 + (cbase ^ ((r & 7) * 8))];
            }
#pragma unroll
            for (int ni = 0; ni < 4; ++ni) {
                const int r = wc + ni * 16 + frow;
                bfr[ni] = *(const bf16x8*)&Bs_[r * 64 + (cbase ^ ((r & 7) * 8))];
            }
#pragma unroll
            for (int mi = 0; mi < 2; ++mi)
#pragma unroll
                for (int ni = 0; ni < 4; ++ni)
                    acc[mi][ni] = __builtin_amdgcn_mfma_f32_16x16x32_bf16(af[mi], bfr[ni], acc[mi][ni], 0, 0, 0);
        }
        __syncthreads();           // drains vmcnt(0): prefetched buf ready
        cur ^= 1;
    }
#undef QKV_STAGE

    if (col0 < 512) {
        // q epilogue: C/D layout col = lane&15, row = quad*4 + reg [m89/m91]
#pragma unroll
        for (int mi = 0; mi < 2; ++mi) {
#pragma unroll
            for (int ni = 0; ni < 4; ++ni) {
                const int c = col0 + wc + ni * 16 + frow;
                const size_t rbase = row0 + wr + mi * 16 + quad * 4;
#pragma unroll
                for (int reg = 0; reg < 4; ++reg)
                    Cq[(rbase + reg) * 512 + c] = f2bf(act_fn(acc[mi][ni][reg]));
            }
        }
        return;
    }

    // ---- kv epilogue (head h = nt-4). KT/VT overlay buf0 (u16 0..10367);
    // the final loop iteration (t=7) computed buf1 (u16 16384..32767) and
    // ended with __syncthreads -> disjoint & ordered.
    u16* KT = SMF;                 // [64][72] k^T
    u16* VT = SMF + 4608;          // [80][72] v^T; row 64 = ones
    for (int i = tid; i < 16 * 72; i += 512)
        VT[64 * 72 + i] = (i < 64) ? (u16)0x3F80 : (u16)0;

    const bool is_k = (wc == 0);   // even waves hold k cols, odd hold v cols
    f32x4 kvacc[5] = {};           // e-tiles; meaningful on waves 0..3

#pragma unroll
    for (int half = 0; half < 2; ++half) {
        __syncthreads();           // prior KT/VT readers (and ones writes) done
        if ((wave >> 2) == half) { // waves 0-3: token rows 0..63; 4-7: 64..127
#pragma unroll
            for (int mi = 0; mi < 2; ++mi) {
                const int n0 = wr + mi * 16 + quad * 4 - half * 64;   // 0..60
#pragma unroll
                for (int ni = 0; ni < 4; ++ni) {
                    const int cl = wc + ni * 16 + frow;               // 0..127
                    u16x4 o2;
#pragma unroll
                    for (int reg = 0; reg < 4; ++reg) {
                        float v = acc[mi][ni][reg];
                        if (is_k) v = act_fn(v);
                        o2[reg] = f2bf(v);
                    }
                    if (is_k) *(u16x4*)&KT[cl * 72 + n0] = o2;
                    else      *(u16x4*)&VT[(cl - 64) * 72 + n0] = o2;
                }
            }
        }
        __syncthreads();
        // kv[d][e] += KT@VT^T over this half's 64 tokens (waves 0-3 only)
        if (wave < 4) {
#pragma unroll
            for (int c = 0; c < 2; ++c) {
                bf16x8 af2 = *(const bf16x8*)&KT[(wave * 16 + frow) * 72 + c * 32 + quad * 8];
#pragma unroll
                for (int et = 0; et < 5; ++et) {
                    bf16x8 bf2 = *(const bf16x8*)&VT[(et * 16 + frow) * 72 + c * 32 + quad * 8];
                    kvacc[et] = __builtin_amdgcn_mfma_f32_16x16x32_bf16(af2, bf2, kvacc[et], 0, 0, 0);
                }
            }
        }
    }

    if (wave < 4) {
        const int b = mt >> 5, h = nt - 4;
        float* dst = kvglob + (size_t)(b * 8 + h) * 5120;
#pragma unroll
        for (int et = 0; et < 5; ++et) {
            const int e = et * 16 + frow;
            if (e <= 64) {
#pragma unroll
                for (int reg = 0; reg < 4; ++reg) {
                    const int d = wave * 16 + quad * 4 + reg;
                    atomicAdd(&dst[d * 80 + e], kvacc[et][reg]);
                }
            }
        }
    }
}

// ---------------------------------------------------------------------------
// make_P: one block per (b,h). P_b[c][h*64+d] = sum_e Wout[c][h*64+e]*kv[d][e]
// via MFMA (A = Wout rows from global, L2-resident; B = kv rows from LDS).
// Also extracts ksum_cat[b][h*64+d] = kvglob col e=64. 512x64x64 GEMM/block.
// ---------------------------------------------------------------------------
__global__ __launch_bounds__(256) void make_P(const float* __restrict__ kvglob,
                                              const u16* __restrict__ wo,
                                              u16* __restrict__ P,
                                              u16* __restrict__ ksum)
{
    __shared__ u16 kvb[64 * 72];   // kv[d][e] bf16, pad 72
    const int bh = blockIdx.x, b = bh >> 3, h = bh & 7;
    const int tid = threadIdx.x, wave = tid >> 6, lane = tid & 63;
    const int frow = lane & 15, quad = lane >> 4;
    const float* src = kvglob + (size_t)bh * 5120;

    for (int i = tid; i < 4096; i += 256)
        kvb[(i >> 6) * 72 + (i & 63)] = f2bf(src[(i >> 6) * 80 + (i & 63)]);
    if (tid < 64) ksum[bh * 64 + tid] = f2bf(src[tid * 80 + 64]);
    __syncthreads();

    f32x4 acc[8][4] = {};          // m = Wout-row tile (wave*128..+128), n = d
    const int m0 = wave * 128;
#pragma unroll
    for (int k2 = 0; k2 < 2; ++k2) {           // e-chunk of 32
        bf16x8 bfr[4];
#pragma unroll
        for (int ni = 0; ni < 4; ++ni)
            bfr[ni] = *(const bf16x8*)&kvb[(ni * 16 + frow) * 72 + k2 * 32 + quad * 8];
#pragma unroll
        for (int mi = 0; mi < 8; ++mi) {
            bf16x8 af = *(const bf16x8*)&wo[(size_t)(m0 + mi * 16 + frow) * 512 + h * 64 + k2 * 32 + quad * 8];
#pragma unroll
            for (int ni = 0; ni < 4; ++ni)
                acc[mi][ni] = __builtin_amdgcn_mfma_f32_16x16x32_bf16(af, bfr[ni], acc[mi][ni], 0, 0, 0);
        }
    }

    u16* Pb = P + (size_t)b * 262144;
#pragma unroll
    for (int mi = 0; mi < 8; ++mi) {
#pragma unroll
        for (int ni = 0; ni < 4; ++ni) {
            const int d = ni * 16 + frow;      // C/D: col = lane&15
#pragma unroll
            for (int reg = 0; reg < 4; ++reg) {
                const int c = m0 + mi * 16 + quad * 4 + reg;
                Pb[(size_t)c * 512 + h * 64 + d] = f2bf(acc[mi][ni][reg]);
            }
        }
    }
}

// ---------------------------------------------------------------------------
// gemm_final: out[t][c] (fp32) = z(t,h-of-i)-scaled GEMM:
//   den[t] (per head-block of K) is computed IN-GEMM: one broadcast-B MFMA
//   per K-subchunk with B[col][k] = ksum[k] for ALL cols -> every acc column
//   holds den(row)... but den must be per-HEAD. K runs over i = h*64+d, and
//   z differs per head! Resolution: scale is applied per head-chunk — see
//   NOTE below: we accumulate den per K-head-chunk and scale partial sums.
// NOTE: z_h(t) multiplies only head h's K-chunk contribution. So we keep a
// SEPARATE fp32 accumulator per K-step pair? No — each head = exactly one
// BK=64 step (K=512 = 8 heads x 64). After each K-step (one head), we fold
// the step's contribution into oacc pre-scaled: oacc += step_acc * z_h.
// step_acc lives in the SAME MFMA accumulator, zeroed per step: cost = 8
// extra VALU fma per acc element per step (2x4x4 x 8 steps).
// den_h(t) = af-row . ksum-chunk via broadcast-B MFMA within the step.
// B matrix is per-batch P (L2-resident). BK=64 + T2 swizzle as gemm_qkv.
// ---------------------------------------------------------------------------
__global__ __launch_bounds__(512, 4) void gemm_final(const u16* __restrict__ A,
                                                     const u16* __restrict__ P,
                                                     float* __restrict__ C,
                                                     const float* __restrict__ bias,
                                                     const u16* __restrict__ ksum)
{
    __shared__ u16 SMF[32768];
    __shared__ u16 ksumL[512];
    const int nt = blockIdx.x;     // 0..3 col-tile
    const int mt = blockIdx.y;     // 0..511 M-tile
    const size_t row0 = (size_t)mt * 128;
    const int col0 = nt * 128;
    const int bb = mt >> 5;
    const u16* Bw = P + (size_t)bb * 262144;
    const int tid  = threadIdx.x;
    const int wave = tid >> 6, lane = tid & 63;
    const int wr = (wave >> 1) * 32, wc = (wave & 1) * 64;
    const int frow = lane & 15, quad = lane >> 4;

    f32x4 oacc[2][4] = {};         // z-scaled running output

    const int ch0 = wave * 64 + lane, ch1 = 512 + ch0;
    const int ar0 = ch0 >> 3, ac0 = ((ch0 & 7) ^ (ar0 & 7)) * 8;
    const int ar1 = ch1 >> 3, ac1 = ((ch1 & 7) ^ (ar1 & 7)) * 8;
    const u16* gA0 = A + (row0 + ar0) * 512 + ac0;
    const u16* gA1 = A + (row0 + ar1) * 512 + ac1;
    const u16* gB0 = Bw + (size_t)(col0 + ar0) * 512 + ac0;
    const u16* gB1 = Bw + (size_t)(col0 + ar1) * 512 + ac1;

#define OUT_STAGE(buf, k0) do {                                   \
        u16* As_ = SMF + (buf) * 16384;                           \
        u16* Bs_ = As_ + 8192;                                    \
        gld16(gA0 + (k0), As_ + wave * 512);                      \
        gld16(gA1 + (k0), As_ + 4096 + wave * 512);               \
        gld16(gB0 + (k0), Bs_ + wave * 512);                      \
        gld16(gB1 + (k0), Bs_ + 4096 + wave * 512);               \
    } while (0)

    OUT_STAGE(0, 0);
    if (tid < 64) *(u16x8*)&ksumL[tid * 8] = *(const u16x8*)&ksum[bb * 512 + tid * 8];
    __syncthreads();
    int cur = 0;
    for (int t = 0; t < 8; ++t) {  // one K-step = one head h = t
        if (t < 7) OUT_STAGE(cur ^ 1, (t + 1) * 64);
        const u16* As_ = SMF + cur * 16384;
        const u16* Bs_ = As_ + 8192;
        f32x4 sacc[2][4] = {};     // this head's unscaled partial
        f32x4 dacc[2] = {};        // den: broadcast-B -> all cols = den(row)
#pragma unroll
        for (int kk = 0; kk < 2; ++kk) {
            const int cbase = kk * 32 + quad * 8;
            bf16x8 af[2], bfr[4];
#pragma unroll
            for (int mi = 0; mi < 2; ++mi) {
                const int r = wr + mi * 16 + frow;
                af[mi] = *(const bf16x8*)&As_[r * 64 + (cbase ^ ((r & 7) * 8))];
            }
#pragma unroll
            for (int ni = 0; ni < 4; ++ni) {
                const int r = wc + ni * 16 + frow;
                bfr[ni] = *(const bf16x8*)&Bs_[r * 64 + (cbase ^ ((r & 7) * 8))];
            }
            bf16x8 kf = *(const bf16x8*)&ksumL[t * 64 + kk * 32 + quad * 8];
#pragma unroll
            for (int mi = 0; mi < 2; ++mi) {
                dacc[mi] = __builtin_amdgcn_mfma_f32_16x16x32_bf16(af[mi], kf, dacc[mi], 0, 0, 0);
#pragma unroll
                for (int ni = 0; ni < 4; ++ni)
                    sacc[mi][ni] = __builtin_amdgcn_mfma_f32_16x16x32_bf16(af[mi], bfr[ni], sacc[mi][ni], 0, 0, 0);
            }
        }
        // fold: oacc += sacc * z_h ; den(row=quad*4+reg) = dacc[mi][reg]
        // (identical across cols since all B-cols = ksum)
#pragma unroll
        for (int mi = 0; mi < 2; ++mi)
#pragma unroll
            for (int reg = 0; reg < 4; ++reg) {
                const float z = 1.0f / fmaxf(dacc[mi][reg], 1e-4f);
#pragma unroll
                for (int ni = 0; ni < 4; ++ni)
                    oacc[mi][ni][reg] += sacc[mi][ni][reg] * z;
            }
        __syncthreads();
        cur ^= 1;
    }
#undef OUT_STAGE

#pragma unroll
    for (int mi = 0; mi < 2; ++mi) {
#pragma unroll
        for (int ni = 0; ni < 4; ++ni) {
            const int c = col0 + wc + ni * 16 + frow;
            const float bv = bias[c];
            const size_t rbase = row0 + wr + mi * 16 + quad * 4;
#pragma unroll
            for (int reg = 0; reg < 4; ++reg)
                C[(rbase + reg) * 512 + c] = oacc[mi][ni][reg] + bv;
        }
    }
}

extern "C" void kernel_launch(void* const* d_in, const int* in_sizes, int n_in,
                              void* d_out, int out_size, void* d_ws, size_t ws_size,
                              hipStream_t stream)
{
    const float* x    = (const float*)d_in[0];   // [65536, 512] fp32
    const float* Wqkv = (const float*)d_in[1];   // [1536, 512]  fp32
    const float* Wout = (const float*)d_in[2];   // [512, 512]   fp32
    const float* bout = (const float*)d_in[3];   // [512]        fp32
    float* out = (float*)d_out;                  // [65536, 512] fp32
    char* ws = (char*)d_ws;

    u16*   wq_bf  = (u16*)ws;                      //   1,572,864 B
    u16*   wo_bf  = (u16*)(ws + 1572864ull);       //     524,288 B
    u16*   wsq    = (u16*)(ws + 2097152ull);       //  67,108,864 B
    u16*   xb     = (u16*)(ws + 69206016ull);      //  67,108,864 B (P reuses this)
    u16*   P      = xb;                            //   8,388,608 B (after gemm_qkv)
    float* kvglob = (float*)(ws + 136314880ull);   //   2,621,440 B
    u16*   ksum   = (u16*)(ws + 138936320ull);     //      65,536 B -> 139,001,856

    // 0) x -> bf16, weights -> bf16 (W_qkv row-permuted), zero kv accumulator
    convert_all<<<17216, 256, 0, stream>>>(x, Wqkv, Wout, xb, wq_bf, wo_bf, kvglob);
    // 1) fused qkv GEMM: q' -> wsq ; per-head kv outer-product -> kvglob
    gemm_qkv<<<dim3(12, 512), 512, 0, stream>>>(xb, wq_bf, wsq, kvglob);
    // 2) P_b = kv_h @ Wout_h (per bh) ; extract ksum  (xb dead -> P reuses it)
    make_P<<<128, 256, 0, stream>>>(kvglob, wo_bf, P, ksum);
    // 3) out = sum_h z_h .* (q' @ P_b^T)_h + b_out  (z fused in-GEMM, fp32)
    gemm_final<<<dim3(4, 512), 512, 0, stream>>>(wsq, P, out, bout, ksum);
}

// Round 11
// 419.644 us; speedup vs baseline: 1.1471x; 1.0694x over previous
//
#include <hip/hip_runtime.h>

// LinearAttention: b=16, n=4096, dim=512, H=8, D=64, inner=512. T=65536 tokens.
// I/O dtype: fp32 (per reference). Compute: bf16 MFMA, fp32 accumulate.
//
// Algebraic form: out[t] = sum_h z_h(t) * (q'_h[t] @ kv_h) @ Wout_h
//                        = (z .* q') @ Pcat,  Pcat_b[c][h*64+d] = sum_e kv_h[d][e] Wout[c][h*64+e]
// z applied to the fp32 accumulator of gemm_final (den via broadcast-B MFMA).
//
// ws layout (~139 MiB):
//   wq_bf  [1536x512 bf16]  W_qkv converted + ROW-PERMUTED (q | per-head k|v)
//   wo_bf  [ 512x512 bf16]  converted W_out
//   wsq    [65536x512 bf16] q' = act(x@Wq^T)  (UNscaled; z applied in gemm_final)
//   xb     [65536x512 bf16] x converted once; REUSED as P after gemm_qkv
//   kvglob [128 x 64x80 f32] kv accumulator (atomicAdd), col e=64 = ksum
//   ksum_bf[16 x 512 bf16]  per-batch concatenated k-sum (h*64+d)
//
// R10 (resubmit — prior run died on container acquisition, not the kernel):
// T1 bijective XCD swizzle on both GEMM grids (single change vs R9-passing).
// gemm_qkv cpx=768: each XCD owns a contiguous 64-mt band, nt fastest -> the
// 12 blocks sharing an x-tile run consecutively on ONE XCD's L2.
// gemm_final cpx=256: 4 same-mt blocks cluster per XCD; per-batch P L2-hot.

typedef unsigned short u16;
typedef u16 u16x4 __attribute__((ext_vector_type(4)));
typedef u16 u16x8 __attribute__((ext_vector_type(8)));
typedef __bf16 bf16x8 __attribute__((ext_vector_type(8)));
typedef float f32x4 __attribute__((ext_vector_type(4)));

__device__ __forceinline__ float bf2f(u16 x) {
    union { unsigned u; float f; } t; t.u = ((unsigned)x) << 16; return t.f;
}
__device__ __forceinline__ u16 f2bf(float f) {
    union { float f; unsigned u; } t; t.f = f;
    unsigned r = t.u + 0x7fffu + ((t.u >> 16) & 1u);   // RNE
    return (u16)(r >> 16);
}
__device__ __forceinline__ float act_fn(float v) {     // 1 + elu
    return v > 0.0f ? v + 1.0f : __expf(v);
}
__device__ __forceinline__ void cvt8(const float* __restrict__ s, u16* __restrict__ d) {
    f32x4 lo = *(const f32x4*)s;
    f32x4 hi = *(const f32x4*)(s + 4);
    u16x8 o = { f2bf(lo[0]), f2bf(lo[1]), f2bf(lo[2]), f2bf(lo[3]),
                f2bf(hi[0]), f2bf(hi[1]), f2bf(hi[2]), f2bf(hi[3]) };
    *(u16x8*)d = o;
}
// async global->LDS, 16B per lane. LDS dest = wave-uniform base + lane*16.
__device__ __forceinline__ void gld16(const u16* g, u16* l) {
    __builtin_amdgcn_global_load_lds(
        (__attribute__((address_space(1))) const void*)g,
        (__attribute__((address_space(3))) void*)l, 16, 0, 0);
}

// ---------------------------------------------------------------------------
// convert_all: x (4,194,304 x8 units) -> xb ; W_qkv (98,304 units) -> wq_bf
// with the head-interleaved row permutation ; W_out (32,768) -> wo_bf ;
// zero kvglob (81,920 f32 = 10,240 x8 units). 17,216 x 256 exact.
// ---------------------------------------------------------------------------
__global__ __launch_bounds__(256) void convert_all(const float* __restrict__ x,
                                                   const float* __restrict__ Wqkv,
                                                   const float* __restrict__ Wout,
                                                   u16* __restrict__ xb,
                                                   u16* __restrict__ wq,
                                                   u16* __restrict__ wo,
                                                   float* __restrict__ kvg)
{
    size_t u = (size_t)blockIdx.x * 256 + threadIdx.x;
    if (u < 4194304ull) {
        cvt8(x + u * 8, xb + u * 8);
    } else if (u < 4292608ull) {
        u -= 4194304ull;                       // dest unit within wq_bf
        const int drow = (int)(u >> 6);
        int srow;
        if (drow < 512) srow = drow;
        else {
            const int t = drow - 512, h = t >> 7, j = t & 127;
            srow = (j < 64) ? (512 + h * 64 + j) : (1024 + h * 64 + (j - 64));
        }
        cvt8(Wqkv + (size_t)srow * 512 + (u & 63) * 8, wq + u * 8);
    } else if (u < 4325376ull) {
        u -= 4292608ull; cvt8(Wout + u * 8, wo + u * 8);
    } else {
        u -= 4325376ull;
        f32x4 z = { 0.f, 0.f, 0.f, 0.f };
        *(f32x4*)&kvg[u * 8] = z;
        *(f32x4*)&kvg[u * 8 + 4] = z;
    }
}

// ---------------------------------------------------------------------------
// gemm_qkv: C128x128 tile of x @ Wqkv_perm^T, K=512, 8 K-steps of BK=64.
// 2-phase __syncthreads double-buffer (proven), 512 thr / 8 waves; wave owns
// 32x64 (acc 2x4). T2 swizzle both-sides (global source pre-swizzled, LDS
// linear, ds_read swizzled). T1 XCD swizzle: o = (id%8)*768 + id/8, nt=o%12,
// mt=o/12 — bijective (6144 = 8*768).
// Col-tiles 0..3 -> q: act + store to wsq.  Col-tiles 4..11 -> head h=nt-4:
// kv epilogue (KT/VT overlay buf0; last compute reads buf1 -> disjoint).
// ---------------------------------------------------------------------------
__global__ __launch_bounds__(512, 4) void gemm_qkv(const u16* __restrict__ A,
                                                   const u16* __restrict__ Bw,
                                                   u16* __restrict__ Cq,
                                                   float* __restrict__ kvglob)
{
    __shared__ u16 SMF[32768];     // 64 KB: buf b at b*16384 (As 8192 | Bs 8192)
    const int id = blockIdx.y * 12 + blockIdx.x;        // linear dispatch id
    const int o  = (id & 7) * 768 + (id >> 3);          // T1 bijective remap
    const int nt = o % 12;         // col-tile (fastest within XCD chunk)
    const int mt = o / 12;         // M-tile
    const size_t row0 = (size_t)mt * 128;
    const int col0 = nt * 128;
    const int tid = threadIdx.x, wave = tid >> 6, lane = tid & 63;
    const int frow = lane & 15, quad = lane >> 4;
    const int wr = (wave >> 1) * 32, wc = (wave & 1) * 64;

    f32x4 acc[2][4] = {};

    // staging chunks (16B each): ch in [0,1024) covers 128x64; row = ch>>3;
    // LDS linear at u16 ch*8; SOURCE col16 = (ch&7)^(row&7)  [T2 involution]
    const int ch0 = wave * 64 + lane, ch1 = 512 + ch0;
    const int ar0 = ch0 >> 3, ac0 = ((ch0 & 7) ^ (ar0 & 7)) * 8;
    const int ar1 = ch1 >> 3, ac1 = ((ch1 & 7) ^ (ar1 & 7)) * 8;
    const u16* gA0 = A + (row0 + ar0) * 512 + ac0;
    const u16* gA1 = A + (row0 + ar1) * 512 + ac1;
    const u16* gB0 = Bw + (size_t)(col0 + ar0) * 512 + ac0;
    const u16* gB1 = Bw + (size_t)(col0 + ar1) * 512 + ac1;

#define QKV_STAGE(buf, k0) do {                                   \
        u16* As_ = SMF + (buf) * 16384;                           \
        u16* Bs_ = As_ + 8192;                                    \
        gld16(gA0 + (k0), As_ + wave * 512);                      \
        gld16(gA1 + (k0), As_ + 4096 + wave * 512);               \
        gld16(gB0 + (k0), Bs_ + wave * 512);                      \
        gld16(gB1 + (k0), Bs_ + 4096 + wave * 512);               \
    } while (0)

    QKV_STAGE(0, 0);
    __syncthreads();               // implicit vmcnt(0): buf0 ready
    int cur = 0;
    for (int t = 0; t < 8; ++t) {
        if (t < 7) QKV_STAGE(cur ^ 1, (t + 1) * 64);    // prefetch next tile
        const u16* As_ = SMF + cur * 16384;
        const u16* Bs_ = As_ + 8192;
#pragma unroll
        for (int kk = 0; kk < 2; ++kk) {
            const int cbase = kk * 32 + quad * 8;
            bf16x8 af[2], bfr[4];
#pragma unroll
            for (int mi = 0; mi < 2; ++mi) {
                const int r = wr + mi * 16 + frow;
                af[mi] = *(const bf16x8*)&As_[r * 64 + (cbase ^ ((r & 7) * 8))];
            }
#pragma unroll
            for (int ni = 0; ni < 4; ++ni) {
                const int r = wc + ni * 16 + frow;
                bfr[ni] = *(const bf16x8*)&Bs_[r * 64 + (cbase ^ ((r & 7) * 8))];
            }
#pragma unroll
            for (int mi = 0; mi < 2; ++mi)
#pragma unroll
                for (int ni = 0; ni < 4; ++ni)
                    acc[mi][ni] = __builtin_amdgcn_mfma_f32_16x16x32_bf16(af[mi], bfr[ni], acc[mi][ni], 0, 0, 0);
        }
        __syncthreads();           // drains vmcnt(0): prefetched buf ready
        cur ^= 1;
    }
#undef QKV_STAGE

    if (col0 < 512) {
        // q epilogue: C/D layout col = lane&15, row = quad*4 + reg [m89/m91]
#pragma unroll
        for (int mi = 0; mi < 2; ++mi) {
#pragma unroll
            for (int ni = 0; ni < 4; ++ni) {
                const int c = col0 + wc + ni * 16 + frow;
                const size_t rbase = row0 + wr + mi * 16 + quad * 4;
#pragma unroll
                for (int reg = 0; reg < 4; ++reg)
                    Cq[(rbase + reg) * 512 + c] = f2bf(act_fn(acc[mi][ni][reg]));
            }
        }
        return;
    }

    // ---- kv epilogue (head h = nt-4). KT/VT overlay buf0 (u16 0..10367);
    // the final loop iteration (t=7) computed buf1 (u16 16384..32767) and
    // ended with __syncthreads -> disjoint & ordered.
    u16* KT = SMF;                 // [64][72] k^T
    u16* VT = SMF + 4608;          // [80][72] v^T; row 64 = ones
    for (int i = tid; i < 16 * 72; i += 512)
        VT[64 * 72 + i] = (i < 64) ? (u16)0x3F80 : (u16)0;

    const bool is_k = (wc == 0);   // even waves hold k cols, odd hold v cols
    f32x4 kvacc[5] = {};           // e-tiles; meaningful on waves 0..3

#pragma unroll
    for (int half = 0; half < 2; ++half) {
        __syncthreads();           // prior KT/VT readers (and ones writes) done
        if ((wave >> 2) == half) { // waves 0-3: token rows 0..63; 4-7: 64..127
#pragma unroll
            for (int mi = 0; mi < 2; ++mi) {
                const int n0 = wr + mi * 16 + quad * 4 - half * 64;   // 0..60
#pragma unroll
                for (int ni = 0; ni < 4; ++ni) {
                    const int cl = wc + ni * 16 + frow;               // 0..127
                    u16x4 o2;
#pragma unroll
                    for (int reg = 0; reg < 4; ++reg) {
                        float v = acc[mi][ni][reg];
                        if (is_k) v = act_fn(v);
                        o2[reg] = f2bf(v);
                    }
                    if (is_k) *(u16x4*)&KT[cl * 72 + n0] = o2;
                    else      *(u16x4*)&VT[(cl - 64) * 72 + n0] = o2;
                }
            }
        }
        __syncthreads();
        // kv[d][e] += KT@VT^T over this half's 64 tokens (waves 0-3 only)
        if (wave < 4) {
#pragma unroll
            for (int c = 0; c < 2; ++c) {
                bf16x8 af2 = *(const bf16x8*)&KT[(wave * 16 + frow) * 72 + c * 32 + quad * 8];
#pragma unroll
                for (int et = 0; et < 5; ++et) {
                    bf16x8 bf2 = *(const bf16x8*)&VT[(et * 16 + frow) * 72 + c * 32 + quad * 8];
                    kvacc[et] = __builtin_amdgcn_mfma_f32_16x16x32_bf16(af2, bf2, kvacc[et], 0, 0, 0);
                }
            }
        }
    }

    if (wave < 4) {
        const int b = mt >> 5, h = nt - 4;
        float* dst = kvglob + (size_t)(b * 8 + h) * 5120;
#pragma unroll
        for (int et = 0; et < 5; ++et) {
            const int e = et * 16 + frow;
            if (e <= 64) {
#pragma unroll
                for (int reg = 0; reg < 4; ++reg) {
                    const int d = wave * 16 + quad * 4 + reg;
                    atomicAdd(&dst[d * 80 + e], kvacc[et][reg]);
                }
            }
        }
    }
}

// ---------------------------------------------------------------------------
// make_P: one block per (b,h). P_b[c][h*64+d] = sum_e Wout[c][h*64+e]*kv[d][e]
// via MFMA (A = Wout rows from global, L2-resident; B = kv rows from LDS).
// Also extracts ksum_cat[b][h*64+d] = kvglob col e=64. 512x64x64 GEMM/block.
// ---------------------------------------------------------------------------
__global__ __launch_bounds__(256) void make_P(const float* __restrict__ kvglob,
                                              const u16* __restrict__ wo,
                                              u16* __restrict__ P,
                                              u16* __restrict__ ksum)
{
    __shared__ u16 kvb[64 * 72];   // kv[d][e] bf16, pad 72
    const int bh = blockIdx.x, b = bh >> 3, h = bh & 7;
    const int tid = threadIdx.x, wave = tid >> 6, lane = tid & 63;
    const int frow = lane & 15, quad = lane >> 4;
    const float* src = kvglob + (size_t)bh * 5120;

    for (int i = tid; i < 4096; i += 256)
        kvb[(i >> 6) * 72 + (i & 63)] = f2bf(src[(i >> 6) * 80 + (i & 63)]);
    if (tid < 64) ksum[bh * 64 + tid] = f2bf(src[tid * 80 + 64]);
    __syncthreads();

    f32x4 acc[8][4] = {};          // m = Wout-row tile (wave*128..+128), n = d
    const int m0 = wave * 128;
#pragma unroll
    for (int k2 = 0; k2 < 2; ++k2) {           // e-chunk of 32
        bf16x8 bfr[4];
#pragma unroll
        for (int ni = 0; ni < 4; ++ni)
            bfr[ni] = *(const bf16x8*)&kvb[(ni * 16 + frow) * 72 + k2 * 32 + quad * 8];
#pragma unroll
        for (int mi = 0; mi < 8; ++mi) {
            bf16x8 af = *(const bf16x8*)&wo[(size_t)(m0 + mi * 16 + frow) * 512 + h * 64 + k2 * 32 + quad * 8];
#pragma unroll
            for (int ni = 0; ni < 4; ++ni)
                acc[mi][ni] = __builtin_amdgcn_mfma_f32_16x16x32_bf16(af, bfr[ni], acc[mi][ni], 0, 0, 0);
        }
    }

    u16* Pb = P + (size_t)b * 262144;
#pragma unroll
    for (int mi = 0; mi < 8; ++mi) {
#pragma unroll
        for (int ni = 0; ni < 4; ++ni) {
            const int d = ni * 16 + frow;      // C/D: col = lane&15
#pragma unroll
            for (int reg = 0; reg < 4; ++reg) {
                const int c = m0 + mi * 16 + quad * 4 + reg;
                Pb[(size_t)c * 512 + h * 64 + d] = f2bf(acc[mi][ni][reg]);
            }
        }
    }
}

// ---------------------------------------------------------------------------
// gemm_final: out[t][c] (fp32): per K-step t (= head h = t), compute the
// step's unscaled partial sacc and den dacc (broadcast-B MFMA vs ksum chunk:
// every acc column = den(row)), then fold oacc += sacc * 1/max(den,eps).
// B matrix is per-batch P (L2-resident). BK=64 + T2 swizzle as gemm_qkv.
// T1 XCD swizzle: o = (id%8)*256 + id/8, nt=o&3, mt=o>>2 (2048 = 8*256).
// ---------------------------------------------------------------------------
__global__ __launch_bounds__(512, 4) void gemm_final(const u16* __restrict__ A,
                                                     const u16* __restrict__ P,
                                                     float* __restrict__ C,
                                                     const float* __restrict__ bias,
                                                     const u16* __restrict__ ksum)
{
    __shared__ u16 SMF[32768];
    __shared__ u16 ksumL[512];
    const int id = blockIdx.y * 4 + blockIdx.x;         // linear dispatch id
    const int o  = (id & 7) * 256 + (id >> 3);          // T1 bijective remap
    const int nt = o & 3;          // col-tile (fastest within XCD chunk)
    const int mt = o >> 2;         // M-tile
    const size_t row0 = (size_t)mt * 128;
    const int col0 = nt * 128;
    const int bb = mt >> 5;
    const u16* Bw = P + (size_t)bb * 262144;
    const int tid  = threadIdx.x;
    const int wave = tid >> 6, lane = tid & 63;
    const int wr = (wave >> 1) * 32, wc = (wave & 1) * 64;
    const int frow = lane & 15, quad = lane >> 4;

    f32x4 oacc[2][4] = {};         // z-scaled running output

    const int ch0 = wave * 64 + lane, ch1 = 512 + ch0;
    const int ar0 = ch0 >> 3, ac0 = ((ch0 & 7) ^ (ar0 & 7)) * 8;
    const int ar1 = ch1 >> 3, ac1 = ((ch1 & 7) ^ (ar1 & 7)) * 8;
    const u16* gA0 = A + (row0 + ar0) * 512 + ac0;
    const u16* gA1 = A + (row0 + ar1) * 512 + ac1;
    const u16* gB0 = Bw + (size_t)(col0 + ar0) * 512 + ac0;
    const u16* gB1 = Bw + (size_t)(col0 + ar1) * 512 + ac1;

#define OUT_STAGE(buf, k0) do {                                   \
        u16* As_ = SMF + (buf) * 16384;                           \
        u16* Bs_ = As_ + 8192;                                    \
        gld16(gA0 + (k0), As_ + wave * 512);                      \
        gld16(gA1 + (k0), As_ + 4096 + wave * 512);               \
        gld16(gB0 + (k0), Bs_ + wave * 512);                      \
        gld16(gB1 + (k0), Bs_ + 4096 + wave * 512);               \
    } while (0)

    OUT_STAGE(0, 0);
    if (tid < 64) *(u16x8*)&ksumL[tid * 8] = *(const u16x8*)&ksum[bb * 512 + tid * 8];
    __syncthreads();
    int cur = 0;
    for (int t = 0; t < 8; ++t) {  // one K-step = one head h = t
        if (t < 7) OUT_STAGE(cur ^ 1, (t + 1) * 64);
        const u16* As_ = SMF + cur * 16384;
        const u16* Bs_ = As_ + 8192;
        f32x4 sacc[2][4] = {};     // this head's unscaled partial
        f32x4 dacc[2] = {};        // den: broadcast-B -> all cols = den(row)
#pragma unroll
        for (int kk = 0; kk < 2; ++kk) {
            const int cbase = kk * 32 + quad * 8;
            bf16x8 af[2], bfr[4];
#pragma unroll
            for (int mi = 0; mi < 2; ++mi) {
                const int r = wr + mi * 16 + frow;
                af[mi] = *(const bf16x8*)&As_[r * 64 + (cbase ^ ((r & 7) * 8))];
            }
#pragma unroll
            for (int ni = 0; ni < 4; ++ni) {
                const int r = wc + ni * 16 + frow;
                bfr[ni] = *(const bf16x8*)&Bs_[r * 64 + (cbase ^ ((r & 7) * 8))];
            }
            bf16x8 kf = *(const bf16x8*)&ksumL[t * 64 + kk * 32 + quad * 8];
#pragma unroll
            for (int mi = 0; mi < 2; ++mi) {
                dacc[mi] = __builtin_amdgcn_mfma_f32_16x16x32_bf16(af[mi], kf, dacc[mi], 0, 0, 0);
#pragma unroll
                for (int ni = 0; ni < 4; ++ni)
                    sacc[mi][ni] = __builtin_amdgcn_mfma_f32_16x16x32_bf16(af[mi], bfr[ni], sacc[mi][ni], 0, 0, 0);
            }
        }
        // fold: oacc += sacc * z_h ; den(row=quad*4+reg) = dacc[mi][reg]
#pragma unroll
        for (int mi = 0; mi < 2; ++mi)
#pragma unroll
            for (int reg = 0; reg < 4; ++reg) {
                const float z = 1.0f / fmaxf(dacc[mi][reg], 1e-4f);
#pragma unroll
                for (int ni = 0; ni < 4; ++ni)
                    oacc[mi][ni][reg] += sacc[mi][ni][reg] * z;
            }
        __syncthreads();
        cur ^= 1;
    }
#undef OUT_STAGE

#pragma unroll
    for (int mi = 0; mi < 2; ++mi) {
#pragma unroll
        for (int ni = 0; ni < 4; ++ni) {
            const int c = col0 + wc + ni * 16 + frow;
            const float bv = bias[c];
            const size_t rbase = row0 + wr + mi * 16 + quad * 4;
#pragma unroll
            for (int reg = 0; reg < 4; ++reg)
                C[(rbase + reg) * 512 + c] = oacc[mi][ni][reg] + bv;
        }
    }
}

extern "C" void kernel_launch(void* const* d_in, const int* in_sizes, int n_in,
                              void* d_out, int out_size, void* d_ws, size_t ws_size,
                              hipStream_t stream)
{
    const float* x    = (const float*)d_in[0];   // [65536, 512] fp32
    const float* Wqkv = (const float*)d_in[1];   // [1536, 512]  fp32
    const float* Wout = (const float*)d_in[2];   // [512, 512]   fp32
    const float* bout = (const float*)d_in[3];   // [512]        fp32
    float* out = (float*)d_out;                  // [65536, 512] fp32
    char* ws = (char*)d_ws;

    u16*   wq_bf  = (u16*)ws;                      //   1,572,864 B
    u16*   wo_bf  = (u16*)(ws + 1572864ull);       //     524,288 B
    u16*   wsq    = (u16*)(ws + 2097152ull);       //  67,108,864 B
    u16*   xb     = (u16*)(ws + 69206016ull);      //  67,108,864 B (P reuses this)
    u16*   P      = xb;                            //   8,388,608 B (after gemm_qkv)
    float* kvglob = (float*)(ws + 136314880ull);   //   2,621,440 B
    u16*   ksum   = (u16*)(ws + 138936320ull);     //      65,536 B -> 139,001,856

    // 0) x -> bf16, weights -> bf16 (W_qkv row-permuted), zero kv accumulator
    convert_all<<<17216, 256, 0, stream>>>(x, Wqkv, Wout, xb, wq_bf, wo_bf, kvglob);
    // 1) fused qkv GEMM: q' -> wsq ; per-head kv outer-product -> kvglob
    gemm_qkv<<<dim3(12, 512), 512, 0, stream>>>(xb, wq_bf, wsq, kvglob);
    // 2) P_b = kv_h @ Wout_h (per bh) ; extract ksum  (xb dead -> P reuses it)
    make_P<<<128, 256, 0, stream>>>(kvglob, wo_bf, P, ksum);
    // 3) out = sum_h z_h .* (q' @ P_b^T)_h + b_out  (z fused in-GEMM, fp32)
    gemm_final<<<dim3(4, 512), 512, 0, stream>>>(wsq, P, out, bout, ksum);
}